// Round 5
// baseline (273.463 us; speedup 1.0000x reference)
//
#include <hip/hip_runtime.h>
#include <hip/hip_bf16.h>
#include <cstdint>

// out[M,N] = x[M,K] @ weight[N,K]^T, fp32 device buffers (fp16 ref -> harness
// float32 path). Single fused kernel: fp32 global -> 2-DEEP reg prefetch ->
// cvt bf16 -> XOR-swizzled double-buffered LDS -> 16x16x32 bf16 MFMA -> fp32 C.
// Round-5 change vs Round-4: K-loop unrolled x2 with two named register
// stages; loads for tile t+2 issued at tile t => issue->use distance ~2 phases
// (~500 clk) covers global latency. Compiler's per-register vmcnt waits become
// counted waits (T4 mechanism); reg-dest loads are NOT drained at s_barrier.
// + T5 setprio around MFMA cluster (phase-diverse waves now exist).

typedef __bf16 bf16x8 __attribute__((ext_vector_type(8)));
typedef float f32x4 __attribute__((ext_vector_type(4)));
typedef unsigned short u16x8 __attribute__((ext_vector_type(8)));

__device__ inline unsigned short f2bf(float f) {
    __hip_bfloat16 h = __float2bfloat16(f);  // RNE
    return *reinterpret_cast<unsigned short*>(&h);
}

// LDS offset (shorts) of (row, 16B-slot), XOR-swizzled: verified conflict-free
// (Round 4: SQ_LDS_BANK_CONFLICT = 0) and bijective per row.
__device__ inline int lds_off(int row, int slot) {
    return row * 32 + (((slot ^ ((row >> 1) & 3)) & 3) << 3);
}

__global__ __launch_bounds__(256) void gemm_bt_fused(
    const float* __restrict__ A,   // x      [M,K]
    const float* __restrict__ B,   // weight [N,K]
    float* __restrict__ C,         // out    [M,N]
    int M, int N, int K)
{
    constexpr int BM = 128, BN = 128, BK = 32;
    __shared__ unsigned short sA[2][BM * BK];  // 2 x 8 KB
    __shared__ unsigned short sB[2][BN * BK];  // 2 x 8 KB

    const int nbm = M / BM;          // 16
    const int nbn = N / BN;          // 64
    const int nwg = nbm * nbn;       // 1024

    // XCD-chunked, bn-major mapping (Round 4: FETCH 1.09 -> 0.73 GB; keep).
    const int bid = blockIdx.x;
    int swz = bid;
    if ((nwg & 7) == 0) {
        const int q = nwg >> 3;
        swz = (bid & 7) * q + (bid >> 3);
    }
    const int bm = swz % nbm;
    const int bn = swz / nbm;

    const int tid = threadIdx.x;

    // ---- staging map: thread covers 16 contiguous floats of one tile row
    const int srow = tid >> 1;           // 0..127
    const int scol = (tid & 1) * 16;     // 0 or 16
    const float* gA = A + (size_t)(bm * BM + srow) * K + scol;
    const float* gB = B + (size_t)(bn * BN + srow) * K + scol;
    const int s0   = (tid & 1) * 2;
    const int wo0  = lds_off(srow, s0);
    const int wo1  = lds_off(srow, s0 + 1);

    // ---- fragment geometry: wave (wr,wc) owns 64x64, acc[4][4] of 16x16
    const int wave = tid >> 6, lane = tid & 63;
    const int wr = wave >> 1, wc = wave & 1;
    const int fr = lane & 15;
    const int slr = lane >> 4;
    int offA[4], offB[4];
#pragma unroll
    for (int i = 0; i < 4; ++i) {
        offA[i] = lds_off(wr * 64 + i * 16 + fr, slr);
        offB[i] = lds_off(wc * 64 + i * 16 + fr, slr);
    }

    f32x4 acc[4][4] = {};
    const int NT = K / BK;               // 128 (even)

    // ---- 2-deep register prefetch stages
    float4 va0[4], vb0[4], va1[4], vb1[4];
#pragma unroll
    for (int p = 0; p < 4; ++p) {        // stage0 <- tile 0
        va0[p] = *reinterpret_cast<const float4*>(gA + p * 4);
        vb0[p] = *reinterpret_cast<const float4*>(gB + p * 4);
    }
#pragma unroll
    for (int p = 0; p < 4; ++p) {        // stage1 <- tile 1
        va1[p] = *reinterpret_cast<const float4*>(gA + BK + p * 4);
        vb1[p] = *reinterpret_cast<const float4*>(gB + BK + p * 4);
    }

    for (int t = 0; t < NT; t += 2) {
        // ================= phase A: tile t (buf0, stage0) =================
        {   // cvt + LDS write (compiler emits counted vmcnt wait for stage0)
            u16x8 pa0, pa1, pb0, pb1;
#pragma unroll
            for (int e = 0; e < 4; ++e) {
                pa0[e] = f2bf(va0[0][e]);  pa0[4 + e] = f2bf(va0[1][e]);
                pa1[e] = f2bf(va0[2][e]);  pa1[4 + e] = f2bf(va0[3][e]);
                pb0[e] = f2bf(vb0[0][e]);  pb0[4 + e] = f2bf(vb0[1][e]);
                pb1[e] = f2bf(vb0[2][e]);  pb1[4 + e] = f2bf(vb0[3][e]);
            }
            *reinterpret_cast<u16x8*>(&sA[0][wo0]) = pa0;
            *reinterpret_cast<u16x8*>(&sA[0][wo1]) = pa1;
            *reinterpret_cast<u16x8*>(&sB[0][wo0]) = pb0;
            *reinterpret_cast<u16x8*>(&sB[0][wo1]) = pb1;
        }
        {   // issue stage0 <- tile t+2 (clamped tail: redundant reload)
            const int kn = (t + 2 < NT) ? (t + 2) * BK : t * BK;
#pragma unroll
            for (int p = 0; p < 4; ++p) {
                va0[p] = *reinterpret_cast<const float4*>(gA + kn + p * 4);
                vb0[p] = *reinterpret_cast<const float4*>(gB + kn + p * 4);
            }
        }
        __syncthreads();   // buf0 writes visible (read->write hazard of buf0
                           // was covered by phase B's barrier last iteration)
        {
            bf16x8 a[4], b[4];
#pragma unroll
            for (int i = 0; i < 4; ++i) a[i] = *reinterpret_cast<const bf16x8*>(&sA[0][offA[i]]);
#pragma unroll
            for (int j = 0; j < 4; ++j) b[j] = *reinterpret_cast<const bf16x8*>(&sB[0][offB[j]]);
            __builtin_amdgcn_s_setprio(1);
#pragma unroll
            for (int i = 0; i < 4; ++i)
#pragma unroll
                for (int j = 0; j < 4; ++j)
                    acc[i][j] = __builtin_amdgcn_mfma_f32_16x16x32_bf16(a[i], b[j], acc[i][j], 0, 0, 0);
            __builtin_amdgcn_s_setprio(0);
        }

        // ================= phase B: tile t+1 (buf1, stage1) =================
        {
            u16x8 pa0, pa1, pb0, pb1;
#pragma unroll
            for (int e = 0; e < 4; ++e) {
                pa0[e] = f2bf(va1[0][e]);  pa0[4 + e] = f2bf(va1[1][e]);
                pa1[e] = f2bf(va1[2][e]);  pa1[4 + e] = f2bf(va1[3][e]);
                pb0[e] = f2bf(vb1[0][e]);  pb0[4 + e] = f2bf(vb1[1][e]);
                pb1[e] = f2bf(vb1[2][e]);  pb1[4 + e] = f2bf(vb1[3][e]);
            }
            *reinterpret_cast<u16x8*>(&sA[1][wo0]) = pa0;
            *reinterpret_cast<u16x8*>(&sA[1][wo1]) = pa1;
            *reinterpret_cast<u16x8*>(&sB[1][wo0]) = pb0;
            *reinterpret_cast<u16x8*>(&sB[1][wo1]) = pb1;
        }
        {   // issue stage1 <- tile t+3 (clamped tail)
            const int kn = (t + 3 < NT) ? (t + 3) * BK : (t + 1) * BK;
#pragma unroll
            for (int p = 0; p < 4; ++p) {
                va1[p] = *reinterpret_cast<const float4*>(gA + kn + p * 4);
                vb1[p] = *reinterpret_cast<const float4*>(gB + kn + p * 4);
            }
        }
        __syncthreads();
        {
            bf16x8 a[4], b[4];
#pragma unroll
            for (int i = 0; i < 4; ++i) a[i] = *reinterpret_cast<const bf16x8*>(&sA[1][offA[i]]);
#pragma unroll
            for (int j = 0; j < 4; ++j) b[j] = *reinterpret_cast<const bf16x8*>(&sB[1][offB[j]]);
            __builtin_amdgcn_s_setprio(1);
#pragma unroll
            for (int i = 0; i < 4; ++i)
#pragma unroll
                for (int j = 0; j < 4; ++j)
                    acc[i][j] = __builtin_amdgcn_mfma_f32_16x16x32_bf16(a[i], b[j], acc[i][j], 0, 0, 0);
            __builtin_amdgcn_s_setprio(0);
        }
    }

    // ---- epilogue: C/D layout col = lane&15, row = (lane>>4)*4 + r (m89)
    const int crow0 = bm * BM + wr * 64 + (lane >> 4) * 4;
    const int ccol0 = bn * BN + wc * 64 + fr;
#pragma unroll
    for (int i = 0; i < 4; ++i)
#pragma unroll
        for (int j = 0; j < 4; ++j)
#pragma unroll
            for (int r = 0; r < 4; ++r)
                C[(size_t)(crow0 + i * 16 + r) * N + (ccol0 + j * 16)] = acc[i][j][r];
}

extern "C" void kernel_launch(void* const* d_in, const int* in_sizes, int n_in,
                              void* d_out, int out_size, void* d_ws, size_t ws_size,
                              hipStream_t stream) {
    const int K = 4096;
    const int M = in_sizes[0] / K;   // 2048
    const int N = in_sizes[1] / K;   // 8192

    const float* x = (const float*)d_in[0];
    const float* w = (const float*)d_in[1];
    float* out     = (float*)d_out;

    const int nwg = (M / 128) * (N / 128);   // 1024
    gemm_bt_fused<<<dim3(nwg), dim3(256), 0, stream>>>(x, w, out, M, N, K);
}

// Round 6
// 265.796 us; speedup vs baseline: 1.0288x; 1.0288x over previous
//
#include <hip/hip_runtime.h>
#include <hip/hip_bf16.h>
#include <hip/hip_cooperative_groups.h>
#include <cstdint>

namespace cg = cooperative_groups;

// out[M,N] = x[M,K] @ weight[N,K]^T, fp32 device buffers.
// Cooperative single kernel:
//   phase 1: fp32 -> bf16 cvt into d_ws (each element converted ONCE)
//   grid.sync()  (device-scope fence: cross-XCD visibility of ws)
//   phase 2: m97-structure bf16 GEMM (global_load_lds w16, 128^2 tile, BK=32,
//            4 waves, 16x16x32 MFMA, bn-major XCD-chunked swizzle), fp32 C.
// Fallback (ws too small / occupancy < 4 blocks/CU): Round-4 fused kernel.

typedef __bf16 bf16x8 __attribute__((ext_vector_type(8)));
typedef float f32x4 __attribute__((ext_vector_type(4)));
typedef unsigned short u16x8 __attribute__((ext_vector_type(8)));

#define GAS __attribute__((address_space(1)))
#define LAS __attribute__((address_space(3)))
#define ASYNC16(gsrc, ldst)                                                  \
    __builtin_amdgcn_global_load_lds((GAS uint32_t*)(const void*)(gsrc),     \
                                     (LAS uint32_t*)(ldst), 16, 0, 0)

__device__ inline unsigned short f2bf(float f) {
    __hip_bfloat16 h = __float2bfloat16(f);  // RNE
    return *reinterpret_cast<unsigned short*>(&h);
}

__global__ __launch_bounds__(256, 4) void coop_cvt_gemm(
    const float* __restrict__ A32,       // x      [M,K]
    const float* __restrict__ B32,       // weight [N,K]
    unsigned short* __restrict__ ws,     // bf16 [szX | szW]
    float* __restrict__ C,               // out    [M,N]
    int M, int N, int K)
{
    const int szX = M * K;               // 8,388,608  (%8==0)
    const int szW = N * K;               // 33,554,432 (%8==0)

    // ---------------- phase 1: cvt fp32 -> bf16 into ws ----------------
    {
        const int total8 = (szX + szW) >> 3;          // 8-elem chunks
        const int S = gridDim.x * blockDim.x;
        for (int c = blockIdx.x * blockDim.x + threadIdx.x; c < total8; c += S) {
            const int base = c << 3;                  // 8-aligned
            const float* src = (base < szX) ? (A32 + base) : (B32 + (base - szX));
            float4 v0 = *reinterpret_cast<const float4*>(src);
            float4 v1 = *reinterpret_cast<const float4*>(src + 4);
            u16x8 o;
            o[0] = f2bf(v0.x); o[1] = f2bf(v0.y); o[2] = f2bf(v0.z); o[3] = f2bf(v0.w);
            o[4] = f2bf(v1.x); o[5] = f2bf(v1.y); o[6] = f2bf(v1.z); o[7] = f2bf(v1.w);
            *reinterpret_cast<u16x8*>(ws + base) = o;
        }
    }

    cg::this_grid().sync();   // all ws writes visible device-wide

    // ---------------- phase 2: m97 bf16 GEMM on ws ----------------
    const unsigned short* __restrict__ A = ws;          // [M,K] bf16
    const unsigned short* __restrict__ B = ws + szX;    // [N,K] bf16

    constexpr int BM = 128, BN = 128, BK = 32;
    __shared__ unsigned short sA[BM * BK];   // 8 KB, linear (global_load_lds)
    __shared__ unsigned short sB[BN * BK];   // 8 KB

    const int nbm = M / BM;          // 16
    const int nbn = N / BN;          // 64
    const int nwg = nbm * nbn;       // 1024 == gridDim.x

    // bn-major XCD-chunked mapping (Round 4: FETCH -31%)
    const int bid = blockIdx.x;
    int swz = bid;
    if ((nwg & 7) == 0) {
        const int q = nwg >> 3;
        swz = (bid & 7) * q + (bid >> 3);
    }
    const int bm = swz % nbm;        // fast: stream A panels
    const int bn = swz / nbm;        // slow: B panel L2-resident

    const int tid  = threadIdx.x;
    const int wave = tid >> 6;
    const int lane = tid & 63;

    // staging: lane covers (row = wave*16 + (lane>>2), k = (lane&3)*8 .. +8)
    const int srow = lane >> 2;
    const int kch  = (lane & 3) * 8;
    const unsigned short* gA0 = A + (size_t)(bm * BM + wave * 16 + srow) * K + kch;
    const unsigned short* gA1 = gA0 + (size_t)64 * K;
    const unsigned short* gB0 = B + (size_t)(bn * BN + wave * 16 + srow) * K + kch;
    const unsigned short* gB1 = gB0 + (size_t)64 * K;
    unsigned short* lA0 = &sA[(wave * 16) * BK];       // wave-uniform bases;
    unsigned short* lA1 = &sA[(64 + wave * 16) * BK];  // HW: base + lane*16B
    unsigned short* lB0 = &sB[(wave * 16) * BK];       // == linear row-major
    unsigned short* lB1 = &sB[(64 + wave * 16) * BK];

    // fragments: wave (wr,wc) owns 64x64, acc[4][4] of 16x16
    const int wr = wave >> 1, wc = wave & 1;
    const int fr = lane & 15;
    const int fk = (lane >> 4) * 8;
    int offA[4], offB[4];
#pragma unroll
    for (int i = 0; i < 4; ++i) {
        offA[i] = (wr * 64 + i * 16 + fr) * BK + fk;
        offB[i] = (wc * 64 + i * 16 + fr) * BK + fk;
    }

    f32x4 acc[4][4] = {};

    for (int k0 = 0; k0 < K; k0 += BK) {
        ASYNC16(gA0 + k0, lA0);
        ASYNC16(gA1 + k0, lA1);
        ASYNC16(gB0 + k0, lB0);
        ASYNC16(gB1 + k0, lB1);
        __syncthreads();   // vmcnt drained before barrier (compiler-enforced)

        bf16x8 a[4], b[4];
#pragma unroll
        for (int i = 0; i < 4; ++i) a[i] = *reinterpret_cast<const bf16x8*>(&sA[offA[i]]);
#pragma unroll
        for (int j = 0; j < 4; ++j) b[j] = *reinterpret_cast<const bf16x8*>(&sB[offB[j]]);
#pragma unroll
        for (int i = 0; i < 4; ++i)
#pragma unroll
            for (int j = 0; j < 4; ++j)
                acc[i][j] = __builtin_amdgcn_mfma_f32_16x16x32_bf16(a[i], b[j], acc[i][j], 0, 0, 0);

        __syncthreads();   // protect sA/sB before next staging
    }

    // epilogue: C/D col = lane&15, row = (lane>>4)*4 + r (m89-verified)
    const int crow0 = bm * BM + wr * 64 + (lane >> 4) * 4;
    const int ccol0 = bn * BN + wc * 64 + fr;
#pragma unroll
    for (int i = 0; i < 4; ++i)
#pragma unroll
        for (int j = 0; j < 4; ++j)
#pragma unroll
            for (int r = 0; r < 4; ++r)
                C[(size_t)(crow0 + i * 16 + r) * N + (ccol0 + j * 16)] = acc[i][j][r];
}

// ---------------- fallback: Round-4 fused kernel (proven PASS, 265 us) ----------------
__device__ inline int lds_off(int row, int slot) {
    return row * 32 + (((slot ^ ((row >> 1) & 3)) & 3) << 3);
}

__global__ __launch_bounds__(256) void gemm_bt_fused(
    const float* __restrict__ A, const float* __restrict__ B,
    float* __restrict__ C, int M, int N, int K)
{
    constexpr int BM = 128, BN = 128, BK = 32;
    __shared__ unsigned short sA[2][BM * BK];
    __shared__ unsigned short sB[2][BN * BK];

    const int nbm = M / BM, nbn = N / BN;
    const int nwg = nbm * nbn;
    const int bid = blockIdx.x;
    int swz = bid;
    if ((nwg & 7) == 0) { const int q = nwg >> 3; swz = (bid & 7) * q + (bid >> 3); }
    const int bm = swz % nbm, bn = swz / nbm;

    const int tid = threadIdx.x;
    const int srow = tid >> 1;
    const int scol = (tid & 1) * 16;
    const float* gA = A + (size_t)(bm * BM + srow) * K + scol;
    const float* gB = B + (size_t)(bn * BN + srow) * K + scol;
    const int s0  = (tid & 1) * 2;
    const int wo0 = lds_off(srow, s0);
    const int wo1 = lds_off(srow, s0 + 1);

    const int wave = tid >> 6, lane = tid & 63;
    const int wr = wave >> 1, wc = wave & 1;
    const int fr = lane & 15;
    const int slr = lane >> 4;
    int offA[4], offB[4];
#pragma unroll
    for (int i = 0; i < 4; ++i) {
        offA[i] = lds_off(wr * 64 + i * 16 + fr, slr);
        offB[i] = lds_off(wc * 64 + i * 16 + fr, slr);
    }

    f32x4 acc[4][4] = {};
    const int NT = K / BK;

    float4 va[4], vb[4];
#pragma unroll
    for (int p = 0; p < 4; ++p) {
        va[p] = *reinterpret_cast<const float4*>(gA + p * 4);
        vb[p] = *reinterpret_cast<const float4*>(gB + p * 4);
    }

    for (int t = 0; t < NT; ++t) {
        const int cur = t & 1;
        u16x8 pa0, pa1, pb0, pb1;
#pragma unroll
        for (int e = 0; e < 4; ++e) {
            pa0[e] = f2bf(va[0][e]);  pa0[4 + e] = f2bf(va[1][e]);
            pa1[e] = f2bf(va[2][e]);  pa1[4 + e] = f2bf(va[3][e]);
            pb0[e] = f2bf(vb[0][e]);  pb0[4 + e] = f2bf(vb[1][e]);
            pb1[e] = f2bf(vb[2][e]);  pb1[4 + e] = f2bf(vb[3][e]);
        }
        *reinterpret_cast<u16x8*>(&sA[cur][wo0]) = pa0;
        *reinterpret_cast<u16x8*>(&sA[cur][wo1]) = pa1;
        *reinterpret_cast<u16x8*>(&sB[cur][wo0]) = pb0;
        *reinterpret_cast<u16x8*>(&sB[cur][wo1]) = pb1;

        const int kn = (t + 1 < NT) ? (t + 1) * BK : t * BK;
#pragma unroll
        for (int p = 0; p < 4; ++p) {
            va[p] = *reinterpret_cast<const float4*>(gA + kn + p * 4);
            vb[p] = *reinterpret_cast<const float4*>(gB + kn + p * 4);
        }

        __syncthreads();

        bf16x8 a[4], b[4];
#pragma unroll
        for (int i = 0; i < 4; ++i) a[i] = *reinterpret_cast<const bf16x8*>(&sA[cur][offA[i]]);
#pragma unroll
        for (int j = 0; j < 4; ++j) b[j] = *reinterpret_cast<const bf16x8*>(&sB[cur][offB[j]]);
#pragma unroll
        for (int i = 0; i < 4; ++i)
#pragma unroll
            for (int j = 0; j < 4; ++j)
                acc[i][j] = __builtin_amdgcn_mfma_f32_16x16x32_bf16(a[i], b[j], acc[i][j], 0, 0, 0);
    }

    const int crow0 = bm * BM + wr * 64 + (lane >> 4) * 4;
    const int ccol0 = bn * BN + wc * 64 + fr;
#pragma unroll
    for (int i = 0; i < 4; ++i)
#pragma unroll
        for (int j = 0; j < 4; ++j)
#pragma unroll
            for (int r = 0; r < 4; ++r)
                C[(size_t)(crow0 + i * 16 + r) * N + (ccol0 + j * 16)] = acc[i][j][r];
}

extern "C" void kernel_launch(void* const* d_in, const int* in_sizes, int n_in,
                              void* d_out, int out_size, void* d_ws, size_t ws_size,
                              hipStream_t stream) {
    int K = 4096;
    int M = in_sizes[0] / K;   // 2048
    int N = in_sizes[1] / K;   // 8192

    const float* x = (const float*)d_in[0];
    const float* w = (const float*)d_in[1];
    float* out     = (float*)d_out;
    unsigned short* wsp = (unsigned short*)d_ws;

    const int nwg = (M / 128) * (N / 128);   // 1024
    const size_t need = ((size_t)in_sizes[0] + (size_t)in_sizes[1]) * 2;

    int maxB = 0;
    hipError_t oe = hipOccupancyMaxActiveBlocksPerMultiprocessor(&maxB, coop_cvt_gemm, 256, 0);
    const bool coop_ok = (oe == hipSuccess) && (ws_size >= need) &&
                         ((long long)maxB * 256 >= (long long)nwg);  // 256 CUs on MI355X

    if (coop_ok) {
        void* args[] = {(void*)&x, (void*)&w, (void*)&wsp, (void*)&out,
                        (void*)&M, (void*)&N, (void*)&K};
        hipError_t le = hipLaunchCooperativeKernel(coop_cvt_gemm, dim3(nwg), dim3(256),
                                                   args, 0, stream);
        if (le == hipSuccess) return;
        // fall through to fallback if cooperative launch was rejected
    }
    gemm_bt_fused<<<dim3(nwg), dim3(256), 0, stream>>>(x, w, out, M, N, K);
}

// Round 7
// 265.261 us; speedup vs baseline: 1.0309x; 1.0020x over previous
//
#include <hip/hip_runtime.h>
#include <hip/hip_bf16.h>
#include <hip/hip_cooperative_groups.h>
#include <cstdint>

namespace cg = cooperative_groups;

// out[M,N] = x[M,K] @ weight[N,K]^T, fp32 device buffers.
// Cooperative kernel, grid 256 x 512thr, 1 block/CU:
//  phase 1: cvt fp32->bf16 into d_ws in TILED+FRAGMENT-ORDERED layout
//           (chunk per (tile,K-step): off = ks*8192 + g*2048 + row*8 + e)
//  grid.sync()
//  phase 2: 256x256 GEMM, BK=64, 8 waves (2x4), 4-phase counted-vmcnt
//           schedule (T3+T4), linear global_load_lds staging (16KB halves),
//           contiguous ds_read_b128 frags, setprio (T5), fp32 C.

typedef __bf16 bf16x8 __attribute__((ext_vector_type(8)));
typedef float f32x4 __attribute__((ext_vector_type(4)));
typedef unsigned short u16x8 __attribute__((ext_vector_type(8)));

#define GAS __attribute__((address_space(1)))
#define LAS __attribute__((address_space(3)))
#define ASYNC16(gsrc, ldst)                                                  \
    __builtin_amdgcn_global_load_lds((GAS uint32_t*)(const void*)(gsrc),     \
                                     (LAS uint32_t*)(ldst), 16, 0, 0)

__device__ inline unsigned short f2bf(float f) {
    __hip_bfloat16 h = __float2bfloat16(f);  // RNE
    return *reinterpret_cast<unsigned short*>(&h);
}

__global__ __launch_bounds__(512, 1) void coop_cvt_gemm2(
    const float* __restrict__ A32,       // x      [M,K]
    const float* __restrict__ B32,       // weight [N,K]
    unsigned short* __restrict__ ws,     // bf16 tiled [szX | szW]
    float* __restrict__ C,               // out    [M,N]
    int M, int N, int K)
{
    const int NT  = K >> 6;              // 64 K-steps
    const int szX = M * K;               // 8.39M
    const int szW = N * K;               // 33.55M

    // ================= phase 1: cvt fp32 -> tiled bf16 ws =================
    // dest-linear walk; chunk = 16384 shorts = one (tile,kt) block.
    // within chunk: c_in (8-short groups): ks=c_in>>10, g=(c_in>>8)&3,
    // row=c_in&255, k = ks*32 + g*8.
    {
        const int nA8 = szX >> 3;
        const int tot8 = (szX + szW) >> 3;
        const int S = gridDim.x * blockDim.x;
        for (int c = blockIdx.x * blockDim.x + threadIdx.x; c < tot8; c += S) {
            const float* src;
            unsigned short* dst = ws + ((size_t)c << 3);
            int cl, rowsPer;  // cl = index within A- or B-region
            const float* base;
            if (c < nA8) { cl = c;        base = A32; }
            else         { cl = c - nA8;  base = B32; }
            const int cid  = cl >> 11;          // chunk id = tile*NT + kt
            const int c_in = cl & 2047;
            const int tile = cid >> 6;          // bm or bn
            const int kt   = cid & 63;
            const int ks   = c_in >> 10;
            const int g    = (c_in >> 8) & 3;
            const int row  = c_in & 255;
            const int k    = ks * 32 + g * 8;
            src = base + (size_t)(tile * 256 + row) * K + kt * 64 + k;
            float4 v0 = *reinterpret_cast<const float4*>(src);
            float4 v1 = *reinterpret_cast<const float4*>(src + 4);
            u16x8 o;
            o[0] = f2bf(v0.x); o[1] = f2bf(v0.y); o[2] = f2bf(v0.z); o[3] = f2bf(v0.w);
            o[4] = f2bf(v1.x); o[5] = f2bf(v1.y); o[6] = f2bf(v1.z); o[7] = f2bf(v1.w);
            *reinterpret_cast<u16x8*>(dst) = o;
        }
    }

    cg::this_grid().sync();
    asm volatile("s_waitcnt vmcnt(0)" ::: "memory");  // clean vmcnt ledger

    // ================= phase 2: GEMM =================
    __shared__ unsigned short lds[2][2][16384];  // [set][A|B][..] = 128 KB

    const int nbm = M >> 8;              // 8
    const int nbn = N >> 8;              // 32
    const int bid = blockIdx.x;
    const int swzid = (bid & 7) * ((nbm * nbn) >> 3) + (bid >> 3);
    const int bm = swzid % nbm;          // fast: stream A panels
    const int bn = swzid / nbm;          // slow: B panel L2-resident

    const int tid  = threadIdx.x;
    const int wv   = tid >> 6;
    const int lane = tid & 63;
    const int wr   = wv >> 2;            // 0..1
    const int wc   = wv & 3;             // 0..3

    // staging source bases (shorts); advance by 16384 per K-step
    const unsigned short* wsA = ws + (size_t)(bm * NT) * 16384 + wv * 1024 + lane * 8;
    const unsigned short* wsB = ws + (size_t)szX + (size_t)(bn * NT) * 16384 + wv * 1024 + lane * 8;
    const int ldsWOff = wv * 1024;       // wave-uniform LDS offset within half

    // fragment read bases (shorts within one op-set)
    const int aBase = (lane >> 4) * 2048 + (wr * 128 + (lane & 15)) * 8;
    const int bBase = (lane >> 4) * 2048 + (wc * 64 + (lane & 15)) * 8;

    f32x4 acc[8][4] = {};

#define STAGE_A(half, tt, ss) do {                                            \
        const unsigned short* s_ = wsA + (size_t)(tt) * 16384 + (half) * 8192;\
        ASYNC16(s_,       &lds[ss][0][(half) * 8192 + ldsWOff]);              \
        ASYNC16(s_ + 512, &lds[ss][0][(half) * 8192 + ldsWOff + 512]);        \
    } while (0)
#define STAGE_B(half, tt, ss) do {                                            \
        const unsigned short* s_ = wsB + (size_t)(tt) * 16384 + (half) * 8192;\
        ASYNC16(s_,       &lds[ss][1][(half) * 8192 + ldsWOff]);              \
        ASYNC16(s_ + 512, &lds[ss][1][(half) * 8192 + ldsWOff + 512]);        \
    } while (0)
#define WAITBAR() do {                                                        \
        asm volatile("s_waitcnt vmcnt(6)" ::: "memory");                      \
        __builtin_amdgcn_s_barrier();                                         \
        __builtin_amdgcn_sched_barrier(0);                                    \
    } while (0)
// one quadrant: 4 a-frags (mh half), 4 b-frags, 16 MFMA
#define PHASE(ss, ks, mh) do {                                                \
        bf16x8 a0 = *(const bf16x8*)&lds[ss][0][(ks)*8192 + aBase + ((mh)*4+0)*128]; \
        bf16x8 a1 = *(const bf16x8*)&lds[ss][0][(ks)*8192 + aBase + ((mh)*4+1)*128]; \
        bf16x8 a2 = *(const bf16x8*)&lds[ss][0][(ks)*8192 + aBase + ((mh)*4+2)*128]; \
        bf16x8 a3 = *(const bf16x8*)&lds[ss][0][(ks)*8192 + aBase + ((mh)*4+3)*128]; \
        bf16x8 b0 = *(const bf16x8*)&lds[ss][1][(ks)*8192 + bBase + 0*128];   \
        bf16x8 b1 = *(const bf16x8*)&lds[ss][1][(ks)*8192 + bBase + 1*128];   \
        bf16x8 b2 = *(const bf16x8*)&lds[ss][1][(ks)*8192 + bBase + 2*128];   \
        bf16x8 b3 = *(const bf16x8*)&lds[ss][1][(ks)*8192 + bBase + 3*128];   \
        __builtin_amdgcn_s_setprio(1);                                        \
        acc[(mh)*4+0][0] = __builtin_amdgcn_mfma_f32_16x16x32_bf16(a0, b0, acc[(mh)*4+0][0], 0, 0, 0); \
        acc[(mh)*4+0][1] = __builtin_amdgcn_mfma_f32_16x16x32_bf16(a0, b1, acc[(mh)*4+0][1], 0, 0, 0); \
        acc[(mh)*4+0][2] = __builtin_amdgcn_mfma_f32_16x16x32_bf16(a0, b2, acc[(mh)*4+0][2], 0, 0, 0); \
        acc[(mh)*4+0][3] = __builtin_amdgcn_mfma_f32_16x16x32_bf16(a0, b3, acc[(mh)*4+0][3], 0, 0, 0); \
        acc[(mh)*4+1][0] = __builtin_amdgcn_mfma_f32_16x16x32_bf16(a1, b0, acc[(mh)*4+1][0], 0, 0, 0); \
        acc[(mh)*4+1][1] = __builtin_amdgcn_mfma_f32_16x16x32_bf16(a1, b1, acc[(mh)*4+1][1], 0, 0, 0); \
        acc[(mh)*4+1][2] = __builtin_amdgcn_mfma_f32_16x16x32_bf16(a1, b2, acc[(mh)*4+1][2], 0, 0, 0); \
        acc[(mh)*4+1][3] = __builtin_amdgcn_mfma_f32_16x16x32_bf16(a1, b3, acc[(mh)*4+1][3], 0, 0, 0); \
        acc[(mh)*4+2][0] = __builtin_amdgcn_mfma_f32_16x16x32_bf16(a2, b0, acc[(mh)*4+2][0], 0, 0, 0); \
        acc[(mh)*4+2][1] = __builtin_amdgcn_mfma_f32_16x16x32_bf16(a2, b1, acc[(mh)*4+2][1], 0, 0, 0); \
        acc[(mh)*4+2][2] = __builtin_amdgcn_mfma_f32_16x16x32_bf16(a2, b2, acc[(mh)*4+2][2], 0, 0, 0); \
        acc[(mh)*4+2][3] = __builtin_amdgcn_mfma_f32_16x16x32_bf16(a2, b3, acc[(mh)*4+2][3], 0, 0, 0); \
        acc[(mh)*4+3][0] = __builtin_amdgcn_mfma_f32_16x16x32_bf16(a3, b0, acc[(mh)*4+3][0], 0, 0, 0); \
        acc[(mh)*4+3][1] = __builtin_amdgcn_mfma_f32_16x16x32_bf16(a3, b1, acc[(mh)*4+3][1], 0, 0, 0); \
        acc[(mh)*4+3][2] = __builtin_amdgcn_mfma_f32_16x16x32_bf16(a3, b2, acc[(mh)*4+3][2], 0, 0, 0); \
        acc[(mh)*4+3][3] = __builtin_amdgcn_mfma_f32_16x16x32_bf16(a3, b3, acc[(mh)*4+3][3], 0, 0, 0); \
        __builtin_amdgcn_s_setprio(0);                                        \
    } while (0)
// one K-step: stage quarters of tile tn into set ss^1, compute set ss.
// vmcnt ledger (per wave, 2 instrs/quarter, FIFO): entry queue = 8
// [A0_s,B0_s,A1_s,B1_s]; p0 +2 -> 10, wait 6 => A0_s,B0_s done; p2: queue
// 8 +2 -> 10, wait 6 => A1_s,B1_s done. Never vmcnt(0) in loop.
#define KSTEP(ss, tn) do {                                                    \
        STAGE_A(0, tn, (ss)^1);  WAITBAR();  PHASE(ss, 0, 0);                 \
        STAGE_B(0, tn, (ss)^1);              PHASE(ss, 0, 1);                 \
        STAGE_A(1, tn, (ss)^1);  WAITBAR();  PHASE(ss, 1, 0);                 \
        STAGE_B(1, tn, (ss)^1);              PHASE(ss, 1, 1);                 \
    } while (0)

    // prologue: tile 0 -> set 0 (queue = 8, matches steady state)
    STAGE_A(0, 0, 0);
    STAGE_B(0, 0, 0);
    STAGE_A(1, 0, 0);
    STAGE_B(1, 0, 0);

    for (int t = 0; t < NT; t += 2) {
        const int tn1 = t + 1;                          // <= NT-1
        KSTEP(0, tn1);
        const int tn2 = (t + 2 < NT) ? t + 2 : NT - 1;  // tail: redundant restage
        KSTEP(1, tn2);
    }

    // ---- epilogue: C/D col = lane&15, row = (lane>>4)*4 + r (m89-verified)
    const int crow0 = bm * 256 + wr * 128 + (lane >> 4) * 4;
    const int ccol0 = bn * 256 + wc * 64 + (lane & 15);
#pragma unroll
    for (int fm = 0; fm < 8; ++fm)
#pragma unroll
        for (int fn = 0; fn < 4; ++fn)
#pragma unroll
            for (int r = 0; r < 4; ++r)
                C[(size_t)(crow0 + fm * 16 + r) * N + (ccol0 + fn * 16)] = acc[fm][fn][r];

#undef STAGE_A
#undef STAGE_B
#undef WAITBAR
#undef PHASE
#undef KSTEP
}

// ---------------- fallback: Round-4 fused kernel (proven PASS) ----------------
__device__ inline int lds_off(int row, int slot) {
    return row * 32 + (((slot ^ ((row >> 1) & 3)) & 3) << 3);
}

__global__ __launch_bounds__(256) void gemm_bt_fused(
    const float* __restrict__ A, const float* __restrict__ B,
    float* __restrict__ C, int M, int N, int K)
{
    constexpr int BM = 128, BN = 128, BK = 32;
    __shared__ unsigned short sA[2][BM * BK];
    __shared__ unsigned short sB[2][BN * BK];

    const int nbm = M / BM, nbn = N / BN;
    const int nwg = nbm * nbn;
    const int bid = blockIdx.x;
    int swz = bid;
    if ((nwg & 7) == 0) { const int q = nwg >> 3; swz = (bid & 7) * q + (bid >> 3); }
    const int bm = swz % nbm, bn = swz / nbm;

    const int tid = threadIdx.x;
    const int srow = tid >> 1;
    const int scol = (tid & 1) * 16;
    const float* gA = A + (size_t)(bm * BM + srow) * K + scol;
    const float* gB = B + (size_t)(bn * BN + srow) * K + scol;
    const int s0  = (tid & 1) * 2;
    const int wo0 = lds_off(srow, s0);
    const int wo1 = lds_off(srow, s0 + 1);

    const int wave = tid >> 6, lane = tid & 63;
    const int wr = wave >> 1, wc = wave & 1;
    const int fr = lane & 15;
    const int slr = lane >> 4;
    int offA[4], offB[4];
#pragma unroll
    for (int i = 0; i < 4; ++i) {
        offA[i] = lds_off(wr * 64 + i * 16 + fr, slr);
        offB[i] = lds_off(wc * 64 + i * 16 + fr, slr);
    }

    f32x4 acc[4][4] = {};
    const int NT = K / BK;

    float4 va[4], vb[4];
#pragma unroll
    for (int p = 0; p < 4; ++p) {
        va[p] = *reinterpret_cast<const float4*>(gA + p * 4);
        vb[p] = *reinterpret_cast<const float4*>(gB + p * 4);
    }

    for (int t = 0; t < NT; ++t) {
        const int cur = t & 1;
        u16x8 pa0, pa1, pb0, pb1;
#pragma unroll
        for (int e = 0; e < 4; ++e) {
            pa0[e] = f2bf(va[0][e]);  pa0[4 + e] = f2bf(va[1][e]);
            pa1[e] = f2bf(va[2][e]);  pa1[4 + e] = f2bf(va[3][e]);
            pb0[e] = f2bf(vb[0][e]);  pb0[4 + e] = f2bf(vb[1][e]);
            pb1[e] = f2bf(vb[2][e]);  pb1[4 + e] = f2bf(vb[3][e]);
        }
        *reinterpret_cast<u16x8*>(&sA[cur][wo0]) = pa0;
        *reinterpret_cast<u16x8*>(&sA[cur][wo1]) = pa1;
        *reinterpret_cast<u16x8*>(&sB[cur][wo0]) = pb0;
        *reinterpret_cast<u16x8*>(&sB[cur][wo1]) = pb1;

        const int kn = (t + 1 < NT) ? (t + 1) * BK : t * BK;
#pragma unroll
        for (int p = 0; p < 4; ++p) {
            va[p] = *reinterpret_cast<const float4*>(gA + kn + p * 4);
            vb[p] = *reinterpret_cast<const float4*>(gB + kn + p * 4);
        }

        __syncthreads();

        bf16x8 a[4], b[4];
#pragma unroll
        for (int i = 0; i < 4; ++i) a[i] = *reinterpret_cast<const bf16x8*>(&sA[cur][offA[i]]);
#pragma unroll
        for (int j = 0; j < 4; ++j) b[j] = *reinterpret_cast<const bf16x8*>(&sB[cur][offB[j]]);
#pragma unroll
        for (int i = 0; i < 4; ++i)
#pragma unroll
            for (int j = 0; j < 4; ++j)
                acc[i][j] = __builtin_amdgcn_mfma_f32_16x16x32_bf16(a[i], b[j], acc[i][j], 0, 0, 0);
    }

    const int crow0 = bm * BM + wr * 64 + (lane >> 4) * 4;
    const int ccol0 = bn * BN + wc * 64 + fr;
#pragma unroll
    for (int i = 0; i < 4; ++i)
#pragma unroll
        for (int j = 0; j < 4; ++j)
#pragma unroll
            for (int r = 0; r < 4; ++r)
                C[(size_t)(crow0 + i * 16 + r) * N + (ccol0 + j * 16)] = acc[i][j][r];
}

extern "C" void kernel_launch(void* const* d_in, const int* in_sizes, int n_in,
                              void* d_out, int out_size, void* d_ws, size_t ws_size,
                              hipStream_t stream) {
    int K = 4096;
    int M = in_sizes[0] / K;   // 2048
    int N = in_sizes[1] / K;   // 8192

    const float* x = (const float*)d_in[0];
    const float* w = (const float*)d_in[1];
    float* out     = (float*)d_out;
    unsigned short* wsp = (unsigned short*)d_ws;

    const size_t need = ((size_t)in_sizes[0] + (size_t)in_sizes[1]) * 2;
    const int nwg2 = (M >> 8) * (N >> 8);   // 256

    bool geom_ok = (M % 256 == 0) && (N % 256 == 0) && (K % 128 == 0);
    int maxB = 0;
    hipError_t oe = hipOccupancyMaxActiveBlocksPerMultiprocessor(&maxB, coop_cvt_gemm2, 512, 0);
    const bool coop_ok = geom_ok && (oe == hipSuccess) && (ws_size >= need) &&
                         ((long long)maxB * 256 >= (long long)nwg2);

    if (coop_ok) {
        void* args[] = {(void*)&x, (void*)&w, (void*)&wsp, (void*)&out,
                        (void*)&M, (void*)&N, (void*)&K};
        hipError_t le = hipLaunchCooperativeKernel(coop_cvt_gemm2, dim3(nwg2), dim3(512),
                                                   args, 0, stream);
        if (le == hipSuccess) return;
    }
    const int nwg = (M / 128) * (N / 128);
    gemm_bt_fused<<<dim3(nwg), dim3(256), 0, stream>>>(x, w, out, M, N, K);
}